// Round 5
// baseline (355.836 us; speedup 1.0000x reference)
//
#include <hip/hip_runtime.h>
#include <math.h>

// Problem constants
#define E_     64     // embedding dim == wavefront size
#define ND_    40     // diseases per visit
#define NM_    30     // medications per visit
#define NSTEP_ 31     // NM+1 decode steps
#define VO_    133    // VM+2 output vocab
#define J3_    192    // 3*E (GRU gates)
#define NROW_  8192   // B*S
#define RPB_   4      // rows per block in main kernel
#define SOS_   131    // VM
#define NC_    388    // sC padded stride (floats); 2-way max conflicts
#define NACT_  325    // combined cols: 192 gh + 133 logits

typedef __attribute__((ext_vector_type(8))) short short8;
typedef __attribute__((ext_vector_type(4))) float f32x4;

__device__ __forceinline__ float sigmoidf_(float x){ return 1.f/(1.f+__expf(-x)); }
__device__ __forceinline__ float tanhf_(float x){
  float ax = fabsf(x);
  float t = 1.f - 2.f/(__expf(2.f*ax)+1.f);   // stable, saturates to 1
  return copysignf(t, x);
}
__device__ __forceinline__ unsigned short f2bf(float f){
  union { float f; unsigned u; } x; x.f = f;
  unsigned r = (x.u + 0x7fffu + ((x.u >> 16) & 1u)) >> 16;  // RNE
  return (unsigned short)r;
}

// Raw barrier: LDS ordering only (s_waitcnt lgkmcnt(0)), NO vmcnt drain.
// __syncthreads() would force vmcnt(0) -> waits for the out[] store acks
// every step. Out stores have no readers; let them fly across steps.
__device__ __forceinline__ void bar_lds(){
  asm volatile("s_waitcnt lgkmcnt(0)" ::: "memory");
  __builtin_amdgcn_s_barrier();
  asm volatile("" ::: "memory");
}

// ---------------------------------------------------------------------------
// Kernel A: P_med[v][j] = sum_e med_table[v][e] * W_ih[j][64+e]   (134x192)
// ---------------------------------------------------------------------------
__global__ __launch_bounds__(256) void k_pmed(const float* __restrict__ mt,
    const float* __restrict__ wih, float* __restrict__ pmed){
  int o = blockIdx.x*256 + threadIdx.x;
  if (o >= 134*J3_) return;
  int v = o / J3_, j = o - v*J3_;
  const float* mr = mt + v*E_;
  const float* wr = wih + j*128 + E_;
  float a = 0.f;
  #pragma unroll
  for (int k=0;k<E_;k++) a = fmaf(mr[k], wr[k], a);
  pmed[o] = a;
}

// ---------------------------------------------------------------------------
// Kernel B: fully fused decoder. 2048 blocks x 256 threads (4 waves),
// 4 rows/block, 1 row/wave; launch_bounds(256,8) -> 8 blocks/CU resident
// (32 waves/CU, 8 independent barrier domains; ~9.4KB LDS each).
// Prologue: step-invariant attention ctx + gi = ctx@W_ih_left^T + biases.
// Main loop: one combined GEMM h(4x64) x [W_hh^T|wo^T](64x325) per step
// (M-tile 16, rows 4..15 zero); 21 n-tiles, 6 per wave as register
// B-fragments (48 VGPR); pointwise GRU + max-free log_softmax (logits
// provably bounded, exp cannot overflow fp32). Raw lgkm-only barriers.
// ---------------------------------------------------------------------------
__global__ __launch_bounds__(256,8) void k_main(
    const int* __restrict__ dis, const float* __restrict__ dmask,
    const float* __restrict__ dt, const float* __restrict__ aw,
    const int* __restrict__ meds,
    const float* __restrict__ whh, const float* __restrict__ bhh,
    const float* __restrict__ wih, const float* __restrict__ bih,
    const float* __restrict__ wo, const float* __restrict__ wob,
    const float* __restrict__ mt, const float* __restrict__ pmed,
    float* __restrict__ out)
{
  __shared__ __align__(16) unsigned short hA[16*E_];    // 2KB swizzled bf16 h
  __shared__ __align__(16) float sC[RPB_*NC_];          // 6.2KB GEMM out
  __shared__ float sSc[RPB_*ND_];                       // 640B attn scores
  __shared__ int sLM[RPB_*32];                          // 512B last-med idx

  const int tid = threadIdx.x;
  const int w = tid >> 6, l = tid & 63;
  const int l15 = l & 15, l4 = l >> 4;
  const int rowbase = blockIdx.x * RPB_;
  const int row = rowbase + w;                          // this wave's row
  const int swz = (((l>>3) ^ w)<<3) + (l&7);            // hA swizzle, row w<8

  {
    int rr = tid / NSTEP_, t = tid - rr*NSTEP_;         // 124 < 256
    if (rr < RPB_)
      sLM[rr*32 + t] = (t==0) ? SOS_ : meds[(size_t)(rowbase+rr)*NM_ + (t-1)];
  }
  for (int i = tid; i < 12*E_; i += 256) hA[RPB_*E_ + i] = 0; // zero rows 4..15

  // ======== prologue: attention ctx (wave-private, 2-pass) ========
  float wd = aw[E_ + l];
  const int*   drow = dis   + (size_t)row*ND_;
  const float* mrow = dmask + (size_t)row*ND_;
  float mx = -INFINITY;
  #pragma unroll 8
  for (int n = 0; n < ND_; ++n){
    float d = dt[(size_t)drow[n]*E_ + l];
    float p = d * wd;
    #pragma unroll
    for (int m=1;m<64;m<<=1) p += __shfl_xor(p, m);
    float scn = p + mrow[n];                // uniform across lanes
    if (l == 0) sSc[w*ND_ + n] = scn;
    mx = fmaxf(mx, scn);
  }
  float ssum = 0.f;
  #pragma unroll 8
  for (int n = 0; n < ND_; ++n){
    float e = __expf(sSc[w*ND_ + n] - mx);  // uniform
    ssum += e;
    if (l == 0) sSc[w*ND_ + n] = e;
  }
  float inv = 1.f/ssum;
  float ctx = 0.f;
  #pragma unroll 8
  for (int n = 0; n < ND_; ++n)
    ctx = fmaf(sSc[w*ND_ + n], dt[(size_t)drow[n]*E_ + l], ctx);
  ctx *= inv;
  hA[w*E_ + swz] = f2bf(ctx);               // stage ctx as A-tile row w
  bar_lds();

  // ======== prologue: gi = ctx @ W_ih_left^T + b_ih (+b_hh r,z) ========
  {
    const int ra = l15;
    short8 A00 = *(const short8*)&hA[ra*E_ + (((l4  ) ^ (ra&7))<<3)];
    short8 A01 = *(const short8*)&hA[ra*E_ + (((l4+4) ^ (ra&7))<<3)];
    #pragma unroll
    for (int j = 0; j < 3; ++j){            // 12 tiles over 4 waves
      int c = (w + 4*j)*16 + l15;
      short8 B0, B1;
      #pragma unroll
      for (int ks = 0; ks < 2; ++ks){
        const float* s = wih + (size_t)c*128 + ks*32 + l4*8;
        short8 f;
        #pragma unroll
        for (int jj=0;jj<8;jj++) f[jj] = (short)f2bf(s[jj]);
        if (ks==0) B0 = f; else B1 = f;
      }
      f32x4 cc = {0.f,0.f,0.f,0.f};
      cc = __builtin_amdgcn_mfma_f32_16x16x32_bf16(A00, B0, cc, 0,0,0);
      cc = __builtin_amdgcn_mfma_f32_16x16x32_bf16(A01, B1, cc, 0,0,0);
      if (l4 == 0){                         // rows 0..3 real
        float add = bih[c] + ((c < 128) ? bhh[c] : 0.f);
        #pragma unroll
        for (int i=0;i<4;i++) sC[i*NC_ + c] = cc[i] + add;
      }
    }
  }
  bar_lds();
  float gia = sC[w*NC_ + l];
  float giz = sC[w*NC_ + l + 64];
  float gin = sC[w*NC_ + l + 128];
  float bhn = bhh[l + 128];
  const bool has2 = (l < 5);
  float wb0 = wob[l], wb1 = wob[l+64], wb2 = has2 ? wob[l+128] : 0.f;
  float hr = mt[SOS_*E_ + l];               // h0 = med_table[SOS]
  hA[w*E_ + swz] = f2bf(hr);                // re-init A-tile row w to h0
  bar_lds();

  // ======== loop-invariant combined-weight B-fragments ========
  // wave w owns n-tiles {w + 4j, j=0..5}; cols: c<192 -> whh, else wo.
  short8 B0[6], B1[6];
  bool act[6];
  #pragma unroll
  for (int j = 0; j < 6; ++j){
    int n = w + 4*j;
    act[j] = (n*16 < NACT_);
    short8 z = {0,0,0,0,0,0,0,0};
    B0[j] = z; B1[j] = z;
    if (act[j]){
      int c = n*16 + l15;
      #pragma unroll
      for (int ks = 0; ks < 2; ++ks){
        int k0 = ks*32 + l4*8;
        float v[8];
        if (c < J3_){
          const float* s = whh + (size_t)c*E_ + k0;
          #pragma unroll
          for (int jj=0;jj<8;jj++) v[jj] = s[jj];
        } else if (c < 192+VO_){
          const float* s = wo + (size_t)(c-192)*E_ + k0;
          #pragma unroll
          for (int jj=0;jj<8;jj++) v[jj] = s[jj];
        } else {
          #pragma unroll
          for (int jj=0;jj<8;jj++) v[jj] = 0.f;
        }
        short8 f;
        #pragma unroll
        for (int jj=0;jj<8;jj++) f[jj] = (short)f2bf(v[jj]);
        if (ks==0) B0[j] = f; else B1[j] = f;
      }
    }
  }

  // ======== main loop ========
  for (int t = 0; t <= NSTEP_; ++t){
    const int ra = l15;
    short8 A00 = *(const short8*)&hA[ra*E_ + (((l4  ) ^ (ra&7))<<3)];
    short8 A01 = *(const short8*)&hA[ra*E_ + (((l4+4) ^ (ra&7))<<3)];
    #pragma unroll
    for (int j = 0; j < 6; ++j){
      if (act[j]){
        f32x4 cc = {0.f,0.f,0.f,0.f};
        cc = __builtin_amdgcn_mfma_f32_16x16x32_bf16(A00, B0[j], cc, 0,0,0);
        cc = __builtin_amdgcn_mfma_f32_16x16x32_bf16(A01, B1[j], cc, 0,0,0);
        int c = (w + 4*j)*16 + l15;
        if (l4 == 0){                       // rows 0..3 real
          #pragma unroll
          for (int i=0;i<4;i++) sC[i*NC_ + c] = cc[i];
        }
      }
    }
    bar_lds();

    if (t < NSTEP_){
      // ---- pointwise GRU for row w (gh = sC cols 0..191) ----
      int lm = sLM[w*32 + t];
      const float* pr = pmed + (size_t)lm*J3_;
      float i_r = gia + pr[l]     + sC[w*NC_ + l];        // biases folded
      float i_z = giz + pr[l+64]  + sC[w*NC_ + l+64];
      float i_n = gin + pr[l+128];
      float hnn = sC[w*NC_ + l+128] + bhn;
      float rg = sigmoidf_(i_r), zg = sigmoidf_(i_z);
      float ng = tanhf_(i_n + rg*hnn);
      hr = (1.f - zg)*ng + zg*hr;
      hA[w*E_ + swz] = f2bf(hr);
    }
    if (t >= 1){
      // ---- max-free log_softmax + store for step t-1 ----
      float l0  = sC[w*NC_ + 192 + l] + wb0;
      float l1  = sC[w*NC_ + 256 + l] + wb1;
      float l2v = sC[w*NC_ + 320 + l] + wb2;
      float s = __expf(l0) + __expf(l1) + (has2 ? __expf(l2v) : 0.f);
      #pragma unroll
      for (int mm=1;mm<64;mm<<=1) s += __shfl_xor(s, mm);
      float lg = __logf(s);
      size_t ob = ((size_t)row*NSTEP_ + (t-1))*VO_;
      out[ob + l]      = l0  - lg;
      out[ob + 64 + l] = l1  - lg;
      if (has2) out[ob + 128 + l] = l2v - lg;
    }
    bar_lds();
  }
}

extern "C" void kernel_launch(void* const* d_in, const int* in_sizes, int n_in,
                              void* d_out, int out_size, void* d_ws, size_t ws_size,
                              hipStream_t stream){
  const int*   dis  = (const int*)  d_in[0];
  const int*   meds = (const int*)  d_in[2];
  const float* dmask= (const float*)d_in[3];
  const float* dt   = (const float*)d_in[6];
  const float* mt   = (const float*)d_in[7];
  const float* aw   = (const float*)d_in[8];
  const float* wih  = (const float*)d_in[10];
  const float* whh  = (const float*)d_in[11];
  const float* bih  = (const float*)d_in[12];
  const float* bhh  = (const float*)d_in[13];
  const float* wo   = (const float*)d_in[14];
  const float* wob  = (const float*)d_in[15];
  float* outp = (float*)d_out;
  float* pmed = (float*)d_ws;                     // 134*192 f32

  k_pmed<<<(134*J3_+255)/256, 256, 0, stream>>>(mt, wih, pmed);
  k_main<<<NROW_/RPB_, 256, 0, stream>>>(dis, dmask, dt, aw, meds,
                                         whh, bhh, wih, bih, wo, wob,
                                         mt, pmed, outp);
}

// Round 6
// 162.858 us; speedup vs baseline: 2.1849x; 2.1849x over previous
//
#include <hip/hip_runtime.h>
#include <math.h>

// Problem constants
#define E_     64     // embedding dim == wavefront size
#define ND_    40     // diseases per visit
#define NM_    30     // medications per visit
#define NSTEP_ 31     // NM+1 decode steps
#define VO_    133    // VM+2 output vocab
#define J3_    192    // 3*E (GRU gates)
#define NROW_  8192   // B*S
#define RPB_   4      // rows per block in k_rnn
#define SOS_   131    // VM
#define NC2_   196    // k_rnn sC stride (floats)
#define SLP_   148    // k_logits sL stride (floats)
#define VROWS_ (NROW_*NSTEP_)   // 253952 virtual rows (row,t)

typedef __attribute__((ext_vector_type(8))) short short8;
typedef __attribute__((ext_vector_type(4))) float f32x4;

__device__ __forceinline__ float sigmoidf_(float x){ return 1.f/(1.f+__expf(-x)); }
__device__ __forceinline__ float tanhf_(float x){
  float ax = fabsf(x);
  float t = 1.f - 2.f/(__expf(2.f*ax)+1.f);   // stable, saturates to 1
  return copysignf(t, x);
}
__device__ __forceinline__ unsigned short f2bf(float f){
  union { float f; unsigned u; } x; x.f = f;
  unsigned r = (x.u + 0x7fffu + ((x.u >> 16) & 1u)) >> 16;  // RNE
  return (unsigned short)r;
}

// Raw barrier: LDS ordering only (s_waitcnt lgkmcnt(0)), NO vmcnt drain.
// Global stores in the loop have no in-kernel readers; let them stay in
// flight across steps instead of draining at every barrier.
__device__ __forceinline__ void bar_lds(){
  asm volatile("s_waitcnt lgkmcnt(0)" ::: "memory");
  __builtin_amdgcn_s_barrier();
  asm volatile("" ::: "memory");
}

// ---------------------------------------------------------------------------
// Kernel A: P_med[v][j] = sum_e med_table[v][e] * W_ih[j][64+e]   (134x192)
// ---------------------------------------------------------------------------
__global__ __launch_bounds__(256) void k_pmed(const float* __restrict__ mt,
    const float* __restrict__ wih, float* __restrict__ pmed){
  int o = blockIdx.x*256 + threadIdx.x;
  if (o >= 134*J3_) return;
  int v = o / J3_, j = o - v*J3_;
  const float* mr = mt + v*E_;
  const float* wr = wih + j*128 + E_;
  float a = 0.f;
  #pragma unroll
  for (int k=0;k<E_;k++) a = fmaf(mr[k], wr[k], a);
  pmed[o] = a;
}

// ---------------------------------------------------------------------------
// Kernel B (serial phase): ctx + gi prologue, then the 31-step h recurrence
// ONLY (no logits). 2048 blocks x 256 threads (4 waves), 1 row/wave.
// 12 N-tiles (192 gh cols) = 3 register B-frag pairs per wave (no spill at
// launch_bounds(256,4); ~55 VGPR -> 8 blocks/CU -> whole grid co-resident).
// h_{t+1} streamed to H (bf16) with never-drained stores (bar_lds).
// ---------------------------------------------------------------------------
__global__ __launch_bounds__(256,4) void k_rnn(
    const int* __restrict__ dis, const float* __restrict__ dmask,
    const float* __restrict__ dt, const float* __restrict__ aw,
    const int* __restrict__ meds,
    const float* __restrict__ whh, const float* __restrict__ bhh,
    const float* __restrict__ wih, const float* __restrict__ bih,
    const float* __restrict__ mt, const float* __restrict__ pmed,
    unsigned short* __restrict__ H)
{
  __shared__ __align__(16) unsigned short hA[16*E_];    // 2KB swizzled bf16 h
  __shared__ __align__(16) float sC[RPB_*NC2_];         // 3.1KB gh out
  __shared__ float sSc[RPB_*ND_];                       // 640B attn scores
  __shared__ int sLM[RPB_*32];                          // 512B last-med idx

  const int tid = threadIdx.x;
  const int w = tid >> 6, l = tid & 63;
  const int l15 = l & 15, l4 = l >> 4;
  const int rowbase = blockIdx.x * RPB_;
  const int row = rowbase + w;                          // this wave's row
  const int swz = (((l>>3) ^ w)<<3) + (l&7);            // hA swizzle, row w<8

  {
    int rr = tid / NSTEP_, t = tid - rr*NSTEP_;         // 124 < 256
    if (rr < RPB_)
      sLM[rr*32 + t] = (t==0) ? SOS_ : meds[(size_t)(rowbase+rr)*NM_ + (t-1)];
  }
  for (int i = tid; i < 12*E_; i += 256) hA[RPB_*E_ + i] = 0; // zero rows 4..15

  // ======== prologue: attention ctx (wave-private, 2-pass) ========
  float wd = aw[E_ + l];
  const int*   drow = dis   + (size_t)row*ND_;
  const float* mrow = dmask + (size_t)row*ND_;
  float mx = -INFINITY;
  #pragma unroll 8
  for (int n = 0; n < ND_; ++n){
    float d = dt[(size_t)drow[n]*E_ + l];
    float p = d * wd;
    #pragma unroll
    for (int m=1;m<64;m<<=1) p += __shfl_xor(p, m);
    float scn = p + mrow[n];                // uniform across lanes
    if (l == 0) sSc[w*ND_ + n] = scn;
    mx = fmaxf(mx, scn);
  }
  float ssum = 0.f;
  #pragma unroll 8
  for (int n = 0; n < ND_; ++n){
    float e = __expf(sSc[w*ND_ + n] - mx);  // uniform
    ssum += e;
    if (l == 0) sSc[w*ND_ + n] = e;
  }
  float inv = 1.f/ssum;
  float ctx = 0.f;
  #pragma unroll 8
  for (int n = 0; n < ND_; ++n)
    ctx = fmaf(sSc[w*ND_ + n], dt[(size_t)drow[n]*E_ + l], ctx);
  ctx *= inv;
  hA[w*E_ + swz] = f2bf(ctx);               // stage ctx as A-tile row w
  bar_lds();

  // ======== prologue: gi = ctx @ W_ih_left^T + b_ih (+b_hh r,z) ========
  {
    const int ra = l15;
    short8 A00 = *(const short8*)&hA[ra*E_ + (((l4  ) ^ (ra&7))<<3)];
    short8 A01 = *(const short8*)&hA[ra*E_ + (((l4+4) ^ (ra&7))<<3)];
    #pragma unroll
    for (int j = 0; j < 3; ++j){            // 12 tiles over 4 waves
      int c = (w + 4*j)*16 + l15;
      short8 B0, B1;
      #pragma unroll
      for (int ks = 0; ks < 2; ++ks){
        const float* s = wih + (size_t)c*128 + ks*32 + l4*8;
        short8 f;
        #pragma unroll
        for (int jj=0;jj<8;jj++) f[jj] = (short)f2bf(s[jj]);
        if (ks==0) B0 = f; else B1 = f;
      }
      f32x4 cc = {0.f,0.f,0.f,0.f};
      cc = __builtin_amdgcn_mfma_f32_16x16x32_bf16(A00, B0, cc, 0,0,0);
      cc = __builtin_amdgcn_mfma_f32_16x16x32_bf16(A01, B1, cc, 0,0,0);
      if (l4 == 0){                         // rows 0..3 real
        float add = bih[c] + ((c < 128) ? bhh[c] : 0.f);
        #pragma unroll
        for (int i=0;i<4;i++) sC[i*NC2_ + c] = cc[i] + add;
      }
    }
  }
  bar_lds();
  float gia = sC[w*NC2_ + l];
  float giz = sC[w*NC2_ + l + 64];
  float gin = sC[w*NC2_ + l + 128];
  float bhn = bhh[l + 128];
  float hr = mt[SOS_*E_ + l];               // h0 = med_table[SOS]
  hA[w*E_ + swz] = f2bf(hr);                // re-init A-tile row w to h0
  bar_lds();

  // ======== loop-invariant W_hh^T B-fragments: wave w tiles {w+4j} ========
  short8 B0[3], B1[3];
  #pragma unroll
  for (int j = 0; j < 3; ++j){
    int c = (w + 4*j)*16 + l15;
    #pragma unroll
    for (int ks = 0; ks < 2; ++ks){
      const float* s = whh + (size_t)c*E_ + ks*32 + l4*8;
      short8 f;
      #pragma unroll
      for (int jj=0;jj<8;jj++) f[jj] = (short)f2bf(s[jj]);
      if (ks==0) B0[j] = f; else B1[j] = f;
    }
  }

  // ======== main recurrence: 31 steps, gh GEMM + pointwise only ========
  size_t hoff = (size_t)row*NSTEP_*E_ + l;  // H[(row*31 + t)*64 + l]
  for (int t = 0; t < NSTEP_; ++t){
    const int ra = l15;
    short8 A00 = *(const short8*)&hA[ra*E_ + (((l4  ) ^ (ra&7))<<3)];
    short8 A01 = *(const short8*)&hA[ra*E_ + (((l4+4) ^ (ra&7))<<3)];
    #pragma unroll
    for (int j = 0; j < 3; ++j){
      f32x4 cc = {0.f,0.f,0.f,0.f};
      cc = __builtin_amdgcn_mfma_f32_16x16x32_bf16(A00, B0[j], cc, 0,0,0);
      cc = __builtin_amdgcn_mfma_f32_16x16x32_bf16(A01, B1[j], cc, 0,0,0);
      int c = (w + 4*j)*16 + l15;
      if (l4 == 0){                         // rows 0..3 real
        #pragma unroll
        for (int i=0;i<4;i++) sC[i*NC2_ + c] = cc[i];
      }
    }
    bar_lds();

    // ---- pointwise GRU for row w ----
    int lm = sLM[w*32 + t];
    const float* pr = pmed + (size_t)lm*J3_;
    float i_r = gia + pr[l]     + sC[w*NC2_ + l];         // biases folded
    float i_z = giz + pr[l+64]  + sC[w*NC2_ + l+64];
    float i_n = gin + pr[l+128];
    float hnn = sC[w*NC2_ + l+128] + bhn;
    float rg = sigmoidf_(i_r), zg = sigmoidf_(i_z);
    float ng = tanhf_(i_n + rg*hnn);
    hr = (1.f - zg)*ng + zg*hr;
    hA[w*E_ + swz] = f2bf(hr);
    H[hoff] = f2bf(hr);                     // h_{t+1}; never drained in-loop
    hoff += E_;
    bar_lds();
  }
}

// ---------------------------------------------------------------------------
// Kernel C (throughput phase): logits + log_softmax for 253,952 independent
// virtual rows (row,t). 7936 blocks x 256 threads (4 waves), 32 vrows/block.
// Stage H-tile (swizzled bf16) -> 2 M-tiles x 9 N-tiles of wo^T via MFMA ->
// max-free log_softmax (logits provably bounded) -> coalesced 135MB write.
// ---------------------------------------------------------------------------
__global__ __launch_bounds__(256,4) void k_logits(
    const unsigned short* __restrict__ H,
    const float* __restrict__ wo, const float* __restrict__ wob,
    float* __restrict__ out)
{
  __shared__ __align__(16) unsigned short sH[32*E_];    // 4KB swizzled bf16
  __shared__ __align__(16) float sL[32*SLP_];           // 18.9KB logits

  const int tid = threadIdx.x;
  const int w = tid >> 6, l = tid & 63;
  const int l15 = l & 15, l4 = l >> 4;
  const size_t vbase = (size_t)blockIdx.x * 32;

  for (int i = tid; i < 32*E_; i += 256){
    int r = i >> 6, k = i & 63;
    sH[r*E_ + (((k>>3) ^ (r&7))<<3) + (k&7)] = H[vbase*E_ + i];
  }
  __syncthreads();

  // A fragments for both M-tiles
  const int ra = l15, rb = 16 + l15;
  short8 A00 = *(const short8*)&sH[ra*E_ + (((l4  ) ^ (ra&7))<<3)];
  short8 A01 = *(const short8*)&sH[ra*E_ + (((l4+4) ^ (ra&7))<<3)];
  short8 A10 = *(const short8*)&sH[rb*E_ + (((l4  ) ^ (rb&7))<<3)];
  short8 A11 = *(const short8*)&sH[rb*E_ + (((l4+4) ^ (rb&7))<<3)];

  // N-tiles: wave w owns {w, w+4, w+8(w==0)} of 9 tiles covering 133 cols
  const int ntile = (w == 0) ? 3 : 2;
  #pragma unroll
  for (int j = 0; j < 3; ++j){
    if (j >= ntile) break;
    int n = w + 4*j;
    int c = n*16 + l15;
    bool valid = (c < VO_);
    short8 B0 = {0,0,0,0,0,0,0,0}, B1 = B0;
    float bv = 0.f;
    if (valid){
      bv = wob[c];
      #pragma unroll
      for (int ks = 0; ks < 2; ++ks){
        const float* s = wo + (size_t)c*E_ + ks*32 + l4*8;
        short8 f;
        #pragma unroll
        for (int jj=0;jj<8;jj++) f[jj] = (short)f2bf(s[jj]);
        if (ks==0) B0 = f; else B1 = f;
      }
    }
    f32x4 c0 = {0.f,0.f,0.f,0.f}, c1 = {0.f,0.f,0.f,0.f};
    c0 = __builtin_amdgcn_mfma_f32_16x16x32_bf16(A00, B0, c0, 0,0,0);
    c0 = __builtin_amdgcn_mfma_f32_16x16x32_bf16(A01, B1, c0, 0,0,0);
    c1 = __builtin_amdgcn_mfma_f32_16x16x32_bf16(A10, B0, c1, 0,0,0);
    c1 = __builtin_amdgcn_mfma_f32_16x16x32_bf16(A11, B1, c1, 0,0,0);
    #pragma unroll
    for (int i=0;i<4;i++) sL[(l4*4+i)*SLP_ + c]      = c0[i] + bv;
    #pragma unroll
    for (int i=0;i<4;i++) sL[(16+l4*4+i)*SLP_ + c]   = c1[i] + bv;
  }
  __syncthreads();

  // ---- max-free log_softmax, 8 vrows per wave ----
  const bool has2 = (l < 5);
  #pragma unroll
  for (int rr8 = 0; rr8 < 8; ++rr8){
    int rr = w*8 + rr8;
    float l0  = sL[rr*SLP_ + l];
    float l1  = sL[rr*SLP_ + 64 + l];
    float l2v = has2 ? sL[rr*SLP_ + 128 + l] : 0.f;
    float s = __expf(l0) + __expf(l1) + (has2 ? __expf(l2v) : 0.f);
    #pragma unroll
    for (int mm=1;mm<64;mm<<=1) s += __shfl_xor(s, mm);
    float lg = __logf(s);
    size_t ob = (vbase + rr)*VO_;
    out[ob + l]      = l0  - lg;
    out[ob + 64 + l] = l1  - lg;
    if (has2) out[ob + 128 + l] = l2v - lg;
  }
}

extern "C" void kernel_launch(void* const* d_in, const int* in_sizes, int n_in,
                              void* d_out, int out_size, void* d_ws, size_t ws_size,
                              hipStream_t stream){
  const int*   dis  = (const int*)  d_in[0];
  const int*   meds = (const int*)  d_in[2];
  const float* dmask= (const float*)d_in[3];
  const float* dt   = (const float*)d_in[6];
  const float* mt   = (const float*)d_in[7];
  const float* aw   = (const float*)d_in[8];
  const float* wih  = (const float*)d_in[10];
  const float* whh  = (const float*)d_in[11];
  const float* bih  = (const float*)d_in[12];
  const float* bhh  = (const float*)d_in[13];
  const float* wo   = (const float*)d_in[14];
  const float* wob  = (const float*)d_in[15];
  float* outp = (float*)d_out;
  float* pmed = (float*)d_ws;                               // 134*192 f32
  unsigned short* Hbuf = (unsigned short*)((float*)d_ws + 134*J3_); // 253952*64 bf16

  k_pmed  <<<(134*J3_+255)/256, 256, 0, stream>>>(mt, wih, pmed);
  k_rnn   <<<NROW_/RPB_,        256, 0, stream>>>(dis, dmask, dt, aw, meds,
                                                  whh, bhh, wih, bih, mt,
                                                  pmed, Hbuf);
  k_logits<<<VROWS_/32,         256, 0, stream>>>(Hbuf, wo, wob, outp);
}

// Round 7
// 147.323 us; speedup vs baseline: 2.4153x; 1.1054x over previous
//
#include <hip/hip_runtime.h>
#include <math.h>

// Problem constants
#define E_     64     // embedding dim == wavefront size
#define ND_    40     // diseases per visit
#define NM_    30     // medications per visit
#define NSTEP_ 31     // NM+1 decode steps
#define VO_    133    // VM+2 output vocab
#define J3_    192    // 3*E (GRU gates)
#define NROW_  8192   // B*S
#define SOS_   131    // VM
#define NCW_   196    // per-wave sC stride (floats)
#define SLP_   148    // k_logits sL stride (floats)
#define VROWS_ (NROW_*NSTEP_)   // 253952 virtual rows (row,t)

typedef __attribute__((ext_vector_type(8))) short short8;
typedef __attribute__((ext_vector_type(4))) float f32x4;

__device__ __forceinline__ float sigmoidf_(float x){ return 1.f/(1.f+__expf(-x)); }
__device__ __forceinline__ float tanhf_(float x){
  float ax = fabsf(x);
  float t = 1.f - 2.f/(__expf(2.f*ax)+1.f);   // stable, saturates to 1
  return copysignf(t, x);
}
__device__ __forceinline__ unsigned short f2bf(float f){
  union { float f; unsigned u; } x; x.f = f;
  unsigned r = (x.u + 0x7fffu + ((x.u >> 16) & 1u)) >> 16;  // RNE
  return (unsigned short)r;
}
// pack 8 consecutive fp32 -> short8 bf16 fragment
__device__ __forceinline__ short8 pack8_(const float* __restrict__ s){
  short8 f;
  #pragma unroll
  for (int j=0;j<8;++j) f[j] = (short)f2bf(s[j]);
  return f;
}

// ---------------------------------------------------------------------------
// Kernel A: P_med[v][j] = sum_e med_table[v][e] * W_ih[j][64+e]   (134x192)
// ---------------------------------------------------------------------------
__global__ __launch_bounds__(256) void k_pmed(const float* __restrict__ mt,
    const float* __restrict__ wih, float* __restrict__ pmed){
  int o = blockIdx.x*256 + threadIdx.x;
  if (o >= 134*J3_) return;
  int v = o / J3_, j = o - v*J3_;
  const float* mr = mt + v*E_;
  const float* wr = wih + j*128 + E_;
  float a = 0.f;
  #pragma unroll
  for (int k=0;k<E_;k++) a = fmaf(mr[k], wr[k], a);
  pmed[o] = a;
}

// ---------------------------------------------------------------------------
// Kernel B (serial phase): BARRIER-FREE recurrence. One wave owns 4 rows
// end-to-end; all cross-lane traffic goes through wave-private LDS (DS ops
// are in-order per wave; no s_barrier anywhere). Per step: 12 W_hh n-tiles
// x 2 MFMA (M=16, A rows = broadcast of the 4 real rows; C rows 4..15 are
// never read), C -> private sC -> redistributed reads; pmed prefetched one
// step ahead into registers (pointwise phase has NO global loads); H
// streamed out bf16, never drained. 512 blocks x 256 thr (4 indep waves).
// launch_bounds(256,2): 12 B-frag pairs = 96 VGPR held, ~175 live, no spill.
// ---------------------------------------------------------------------------
__global__ __launch_bounds__(256,2) void k_rnn(
    const int* __restrict__ dis, const float* __restrict__ dmask,
    const float* __restrict__ dt, const float* __restrict__ aw,
    const int* __restrict__ meds,
    const float* __restrict__ whh, const float* __restrict__ bhh,
    const float* __restrict__ wih, const float* __restrict__ bih,
    const float* __restrict__ mt, const float* __restrict__ pmed,
    unsigned short* __restrict__ H)
{
  __shared__ __align__(16) unsigned short hAall[4][4*80]; // 640B/wave, bf16 h
  __shared__ __align__(16) float sCall[4][4*NCW_];        // 3.1KB/wave C out
  __shared__ int sLMall[4][128];                          // last-med idx

  const int tid = threadIdx.x;
  const int w = tid >> 6, l = tid & 63;
  const int l15 = l & 15, l4 = l >> 4;
  const int ral = l15 & 3;                 // A-row source (broadcast rows 0..3)
  const int rbase = blockIdx.x*16 + w*4;   // this wave's 4 rows
  unsigned short* myA = hAall[w];
  float*          myC = sCall[w];
  int*            myL = sLMall[w];

  // ---- last-med indices for 4 rows x 31 steps (wave-private) ----
  #pragma unroll
  for (int i = l; i < 128; i += 64){
    int rr = i >> 5, t = i & 31;
    if (t < NSTEP_)
      myL[i] = (t==0) ? SOS_ : meds[(size_t)(rbase+rr)*NM_ + (t-1)];
  }

  // ======== prologue: attention ctx for rows 0..3 (fused 2-pass) ========
  // attn = softmax(d_score + d_mask) is h-independent (uniform shift).
  float wd = aw[E_ + l];
  #pragma unroll 1
  for (int r = 0; r < 4; ++r){
    const int*   drow = dis   + (size_t)(rbase+r)*ND_;
    const float* mrow = dmask + (size_t)(rbase+r)*ND_;
    float dreg[ND_], sc[ND_];
    float mx = -INFINITY;
    #pragma unroll
    for (int n = 0; n < ND_; ++n){
      float d = dt[(size_t)drow[n]*E_ + l];
      dreg[n] = d;
      float p = d * wd;
      #pragma unroll
      for (int m=1;m<64;m<<=1) p += __shfl_xor(p, m);
      sc[n] = p + mrow[n];                 // uniform across lanes
      mx = fmaxf(mx, sc[n]);
    }
    float ss = 0.f, ctx = 0.f;
    #pragma unroll
    for (int n = 0; n < ND_; ++n){
      float e = __expf(sc[n]-mx);
      ss += e;
      ctx = fmaf(e, dreg[n], ctx);         // softmax is linear in weights
    }
    ctx /= ss;
    myA[r*80 + l] = f2bf(ctx);             // stage ctx row (linear layout)
  }

  // ======== prologue: gi = ctx @ W_ih_left^T (wave-private MFMA) ========
  {
    short8 A00 = *(const short8*)&myA[ral*80 + l4*8];
    short8 A01 = *(const short8*)&myA[ral*80 + l4*8 + 32];
    #pragma unroll 1
    for (int j = 0; j < 12; ++j){
      int c = j*16 + l15;
      short8 B0 = pack8_(wih + (size_t)c*128 + l4*8);
      short8 B1 = pack8_(wih + (size_t)c*128 + 32 + l4*8);
      f32x4 cc = {0.f,0.f,0.f,0.f};
      cc = __builtin_amdgcn_mfma_f32_16x16x32_bf16(A00, B0, cc, 0,0,0);
      cc = __builtin_amdgcn_mfma_f32_16x16x32_bf16(A01, B1, cc, 0,0,0);
      if (l4 == 0){
        #pragma unroll
        for (int i=0;i<4;i++) myC[i*NCW_ + c] = cc[i];
      }
    }
  }
  // redistribute: lane -> row l4, cols 4*l15 + {0,64,128}; fold biases
  f32x4 gi_r = *(const f32x4*)&myC[l4*NCW_ + 4*l15];
  f32x4 gi_z = *(const f32x4*)&myC[l4*NCW_ + 4*l15 + 64];
  f32x4 gi_n = *(const f32x4*)&myC[l4*NCW_ + 4*l15 + 128];
  f32x4 bihr = *(const f32x4*)&bih[4*l15];
  f32x4 bihz = *(const f32x4*)&bih[4*l15 + 64];
  f32x4 bihn = *(const f32x4*)&bih[4*l15 + 128];
  f32x4 bhhr = *(const f32x4*)&bhh[4*l15];
  f32x4 bhhz = *(const f32x4*)&bhh[4*l15 + 64];
  f32x4 bhn  = *(const f32x4*)&bhh[4*l15 + 128];
  #pragma unroll
  for (int i=0;i<4;++i){
    gi_r[i] += bihr[i] + bhhr[i];
    gi_z[i] += bihz[i] + bhhz[i];
    gi_n[i] += bihn[i];
  }

  // ======== loop-invariant W_hh^T B-fragments: all 12 tiles (96 VGPR) ====
  short8 WB0[12], WB1[12];
  #pragma unroll
  for (int j = 0; j < 12; ++j){
    int c = j*16 + l15;
    WB0[j] = pack8_(whh + (size_t)c*E_ + l4*8);
    WB1[j] = pack8_(whh + (size_t)c*E_ + 32 + l4*8);
  }

  // ======== h0 = med_table[SOS]; lane holds row l4, dims 4*l15..+3 ========
  f32x4 hrv = *(const f32x4*)&mt[SOS_*E_ + 4*l15];
  {
    uint2 hv;
    hv.x = (unsigned)f2bf(hrv[0]) | ((unsigned)f2bf(hrv[1])<<16);
    hv.y = (unsigned)f2bf(hrv[2]) | ((unsigned)f2bf(hrv[3])<<16);
    *(uint2*)&myA[l4*80 + 4*l15] = hv;
  }

  // ---- prefetch pmed for t=0 ----
  int lm0 = myL[l4*32];
  f32x4 p_r = *(const f32x4*)&pmed[(size_t)lm0*J3_ + 4*l15];
  f32x4 p_z = *(const f32x4*)&pmed[(size_t)lm0*J3_ + 4*l15 + 64];
  f32x4 p_n = *(const f32x4*)&pmed[(size_t)lm0*J3_ + 4*l15 + 128];

  // ======== main recurrence: 31 steps, ZERO barriers ========
  size_t hbase = (size_t)(rbase + l4)*NSTEP_*E_ + 4*l15;
  for (int t = 0; t < NSTEP_; ++t){
    // A-frags: broadcast reads of the 4 real rows (C rows 4..15 unused)
    short8 A00 = *(const short8*)&myA[ral*80 + l4*8];
    short8 A01 = *(const short8*)&myA[ral*80 + l4*8 + 32];
    int lmn = (t+1 < NSTEP_) ? myL[l4*32 + t + 1] : 0;
    #pragma unroll
    for (int j = 0; j < 12; ++j){
      f32x4 cc = {0.f,0.f,0.f,0.f};
      cc = __builtin_amdgcn_mfma_f32_16x16x32_bf16(A00, WB0[j], cc, 0,0,0);
      cc = __builtin_amdgcn_mfma_f32_16x16x32_bf16(A01, WB1[j], cc, 0,0,0);
      if (l4 == 0){
        int c = j*16 + l15;
        myC[0*NCW_ + c] = cc[0];
        myC[1*NCW_ + c] = cc[1];
        myC[2*NCW_ + c] = cc[2];
        myC[3*NCW_ + c] = cc[3];
      }
    }
    // redistribute gh (wave-private LDS; DS in-order, auto lgkmcnt)
    f32x4 ghr = *(const f32x4*)&myC[l4*NCW_ + 4*l15];
    f32x4 ghz = *(const f32x4*)&myC[l4*NCW_ + 4*l15 + 64];
    f32x4 ghn = *(const f32x4*)&myC[l4*NCW_ + 4*l15 + 128];
    // pointwise GRU: 4 dims of row (rbase+l4); pmed from prefetch regs
    #pragma unroll
    for (int i=0;i<4;++i){
      float ir  = gi_r[i] + p_r[i] + ghr[i];
      float iz  = gi_z[i] + p_z[i] + ghz[i];
      float in2 = gi_n[i] + p_n[i];
      float hn  = ghn[i] + bhn[i];
      float rg = sigmoidf_(ir), zg = sigmoidf_(iz);
      float ng = tanhf_(in2 + rg*hn);
      hrv[i] = (1.f - zg)*ng + zg*hrv[i];
    }
    uint2 hv;
    hv.x = (unsigned)f2bf(hrv[0]) | ((unsigned)f2bf(hrv[1])<<16);
    hv.y = (unsigned)f2bf(hrv[2]) | ((unsigned)f2bf(hrv[3])<<16);
    *(uint2*)&myA[l4*80 + 4*l15] = hv;        // h_{t+1} for next A-frags
    *(uint2*)&H[hbase + (size_t)t*E_] = hv;   // stream out; never drained
    if (t+1 < NSTEP_){                        // prefetch pmed for t+1
      p_r = *(const f32x4*)&pmed[(size_t)lmn*J3_ + 4*l15];
      p_z = *(const f32x4*)&pmed[(size_t)lmn*J3_ + 4*l15 + 64];
      p_n = *(const f32x4*)&pmed[(size_t)lmn*J3_ + 4*l15 + 128];
    }
  }
}

// ---------------------------------------------------------------------------
// Kernel C (throughput phase): logits + log_softmax for 253,952 independent
// virtual rows (row,t). 7936 blocks x 256 threads (4 waves), 32 vrows/block.
// Stage H-tile (swizzled bf16) -> 2 M-tiles x 9 N-tiles of wo^T via MFMA ->
// max-free log_softmax (logits provably bounded) -> coalesced 135MB write.
// ---------------------------------------------------------------------------
__global__ __launch_bounds__(256,4) void k_logits(
    const unsigned short* __restrict__ H,
    const float* __restrict__ wo, const float* __restrict__ wob,
    float* __restrict__ out)
{
  __shared__ __align__(16) unsigned short sH[32*E_];    // 4KB swizzled bf16
  __shared__ __align__(16) float sL[32*SLP_];           // 18.9KB logits

  const int tid = threadIdx.x;
  const int w = tid >> 6, l = tid & 63;
  const int l15 = l & 15, l4 = l >> 4;
  const size_t vbase = (size_t)blockIdx.x * 32;

  for (int i = tid; i < 32*E_; i += 256){
    int r = i >> 6, k = i & 63;
    sH[r*E_ + (((k>>3) ^ (r&7))<<3) + (k&7)] = H[vbase*E_ + i];
  }
  __syncthreads();

  // A fragments for both M-tiles
  const int ra = l15, rb = 16 + l15;
  short8 A00 = *(const short8*)&sH[ra*E_ + (((l4  ) ^ (ra&7))<<3)];
  short8 A01 = *(const short8*)&sH[ra*E_ + (((l4+4) ^ (ra&7))<<3)];
  short8 A10 = *(const short8*)&sH[rb*E_ + (((l4  ) ^ (rb&7))<<3)];
  short8 A11 = *(const short8*)&sH[rb*E_ + (((l4+4) ^ (rb&7))<<3)];

  // N-tiles: wave w owns {w, w+4, w+8(w==0)} of 9 tiles covering 133 cols
  const int ntile = (w == 0) ? 3 : 2;
  #pragma unroll
  for (int j = 0; j < 3; ++j){
    if (j >= ntile) break;
    int n = w + 4*j;
    int c = n*16 + l15;
    bool valid = (c < VO_);
    short8 B0 = {0,0,0,0,0,0,0,0}, B1 = B0;
    float bv = 0.f;
    if (valid){
      bv = wob[c];
      B0 = pack8_(wo + (size_t)c*E_ + l4*8);
      B1 = pack8_(wo + (size_t)c*E_ + 32 + l4*8);
    }
    f32x4 c0 = {0.f,0.f,0.f,0.f}, c1 = {0.f,0.f,0.f,0.f};
    c0 = __builtin_amdgcn_mfma_f32_16x16x32_bf16(A00, B0, c0, 0,0,0);
    c0 = __builtin_amdgcn_mfma_f32_16x16x32_bf16(A01, B1, c0, 0,0,0);
    c1 = __builtin_amdgcn_mfma_f32_16x16x32_bf16(A10, B0, c1, 0,0,0);
    c1 = __builtin_amdgcn_mfma_f32_16x16x32_bf16(A11, B1, c1, 0,0,0);
    #pragma unroll
    for (int i=0;i<4;i++) sL[(l4*4+i)*SLP_ + c]      = c0[i] + bv;
    #pragma unroll
    for (int i=0;i<4;i++) sL[(16+l4*4+i)*SLP_ + c]   = c1[i] + bv;
  }
  __syncthreads();

  // ---- max-free log_softmax, 8 vrows per wave ----
  const bool has2 = (l < 5);
  #pragma unroll
  for (int rr8 = 0; rr8 < 8; ++rr8){
    int rr = w*8 + rr8;
    float l0  = sL[rr*SLP_ + l];
    float l1  = sL[rr*SLP_ + 64 + l];
    float l2v = has2 ? sL[rr*SLP_ + 128 + l] : 0.f;
    float s = __expf(l0) + __expf(l1) + (has2 ? __expf(l2v) : 0.f);
    #pragma unroll
    for (int mm=1;mm<64;mm<<=1) s += __shfl_xor(s, mm);
    float lg = __logf(s);
    size_t ob = (vbase + rr)*VO_;
    out[ob + l]      = l0  - lg;
    out[ob + 64 + l] = l1  - lg;
    if (has2) out[ob + 128 + l] = l2v - lg;
  }
}

extern "C" void kernel_launch(void* const* d_in, const int* in_sizes, int n_in,
                              void* d_out, int out_size, void* d_ws, size_t ws_size,
                              hipStream_t stream){
  const int*   dis  = (const int*)  d_in[0];
  const int*   meds = (const int*)  d_in[2];
  const float* dmask= (const float*)d_in[3];
  const float* dt   = (const float*)d_in[6];
  const float* mt   = (const float*)d_in[7];
  const float* aw   = (const float*)d_in[8];
  const float* wih  = (const float*)d_in[10];
  const float* whh  = (const float*)d_in[11];
  const float* bih  = (const float*)d_in[12];
  const float* bhh  = (const float*)d_in[13];
  const float* wo   = (const float*)d_in[14];
  const float* wob  = (const float*)d_in[15];
  float* outp = (float*)d_out;
  float* pmed = (float*)d_ws;                               // 134*192 f32
  unsigned short* Hbuf = (unsigned short*)((float*)d_ws + 134*J3_); // 253952*64 bf16

  k_pmed  <<<(134*J3_+255)/256, 256, 0, stream>>>(mt, wih, pmed);
  k_rnn   <<<NROW_/16,          256, 0, stream>>>(dis, dmask, dt, aw, meds,
                                                  whh, bhh, wih, bih, mt,
                                                  pmed, Hbuf);
  k_logits<<<VROWS_/32,         256, 0, stream>>>(Hbuf, wo, wob, outp);
}